// Round 3
// baseline (6860.446 us; speedup 1.0000x reference)
//
#include <hip/hip_runtime.h>
#include <hip/hip_fp16.h>

#define GD 256   // grid -- 1 WG per CU
#define BD 1024  // 16 waves/CU

constexpr int TSTEPS = 256;
constexpr int DD = 512;
constexpr int KK4 = 2048;
constexpr int LC = 128;

// ---- ws float offsets ----
constexpr size_t OFF_FLAGS_F = 0;        // 256 flag lines (stride 32 ints)
constexpr size_t OFF_REL_F   = 8192;     // 8 release lines
constexpr size_t OFF_SEXPR   = 24832;    // [32][128] f32 exp-score exchange
constexpr size_t OFF_H16_F   = 28928;    // h16 region base
// ---- h16-unit offsets ----
constexpr size_t HO_X16   = 0;           // [256 st][32 ch][32 b][16] fp16(x)
constexpr size_t HO_ATT   = 4194304;     // [32*128][512] att_ctx fp16
constexpr size_t HO_HRING = 6291456;     // [256 step][32 ch][32 b][16] h ring
constexpr size_t HO_CTX16 = 10485760;    // [32 ch][4096 r][16] fp16(ctx)
constexpr size_t HO_WH16  = 12582912;    // [64 kpg][512 a][4 slot] h2 (= 262144 h16)
constexpr size_t HO_PACK  = 12845056;    // [256][12288] per-WG packed weights
constexpr size_t HO_CTXV  = 15990784;    // [256][128 l][32 b][8 cc] per-WG ctx@V
constexpr int PACKSZ = 12288;            // 8W+8U+8V cols (kp-major)

typedef _Float16 h16;
typedef _Float16 h2  __attribute__((ext_vector_type(2)));
typedef _Float16 h8v __attribute__((ext_vector_type(8)));
union H8  { h8v v; h2 p[4]; };
union H2U { h2 h; unsigned u; };
union HSU { h16 h; unsigned short u; };

__device__ __forceinline__ float rcp_fast(float x) { return __builtin_amdgcn_rcpf(x); }
__device__ __forceinline__ float ftanh(float x) {
  float e = __expf(2.0f * x);
  return 1.0f - 2.0f * rcp_fast(e + 1.0f);
}
__device__ __forceinline__ float fsig(float x) { return rcp_fast(1.0f + __expf(-x)); }
__device__ __forceinline__ float fdot2(h2 a, h2 b, float c) {
  return __builtin_amdgcn_fdot2(a, b, c, false);
}

// agent-scope coherent ops (bypass L1/L2, land at MALL)
__device__ __forceinline__ float cloadf(const float* p) {
  return __hip_atomic_load(p, __ATOMIC_RELAXED, __HIP_MEMORY_SCOPE_AGENT);
}
__device__ __forceinline__ void cstoref(float* p, float v) {
  __hip_atomic_store(p, v, __ATOMIC_RELAXED, __HIP_MEMORY_SCOPE_AGENT);
}
__device__ __forceinline__ void cstoreu(unsigned* p, unsigned v) {
  __hip_atomic_store(p, v, __ATOMIC_RELAXED, __HIP_MEMORY_SCOPE_AGENT);
}
__device__ __forceinline__ void cstoreu8(unsigned long long* p, unsigned long long v) {
  __hip_atomic_store(p, v, __ATOMIC_RELAXED, __HIP_MEMORY_SCOPE_AGENT);
}
__device__ __forceinline__ void cstores(h16* p, h16 v) {
  HSU s; s.h = v;
  __hip_atomic_store((unsigned short*)p, s.u, __ATOMIC_RELAXED,
                     __HIP_MEMORY_SCOPE_AGENT);
}

// grid barrier, no atomic RMW
__device__ __forceinline__ void gsync(int* flags, int* rel, int w, int& gen) {
  __syncthreads();
  gen++;
  const int t = threadIdx.x;
  if (w == 0) {
    if (t < 64) {
      if (t == 0)
        __hip_atomic_store(flags, gen, __ATOMIC_RELAXED, __HIP_MEMORY_SCOPE_AGENT);
      for (;;) {
        int m = gen;
#pragma unroll
        for (int i = 0; i < 4; i++) {
          int v = __hip_atomic_load(flags + (t + i * 64) * 32,
                                    __ATOMIC_RELAXED, __HIP_MEMORY_SCOPE_AGENT);
          m = (v < m) ? v : m;
        }
        if (__all(m >= gen)) break;
      }
      if (t == 0) {
#pragma unroll
        for (int i = 0; i < 8; i++)
          __hip_atomic_store(rel + i * 32, gen, __ATOMIC_RELAXED,
                             __HIP_MEMORY_SCOPE_AGENT);
      }
    }
    asm volatile("" ::: "memory");
  } else {
    if (t == 0) {
      __hip_atomic_store(flags + w * 32, gen, __ATOMIC_RELAXED,
                         __HIP_MEMORY_SCOPE_AGENT);
      const int* r = rel + (w & 7) * 32;
      while (__hip_atomic_load(r, __ATOMIC_RELAXED, __HIP_MEMORY_SCOPE_AGENT) < gen)
        __builtin_amdgcn_s_sleep(1);
    }
    asm volatile("" ::: "memory");
  }
  __syncthreads();
}

// 8-col GEMV partial over this thread's 8 k-pairs; vec in padded LDS (stride 514)
__device__ __forceinline__ void mac8(const h16* vec, const h16* P, int s, int b,
                                     float* acc) {
  const h16* vrow = vec + b * 514 + 16 * s;
  const h16* Pp = P + (size_t)(8 * s) * 16;
#pragma unroll
  for (int q = 0; q < 8; q++) {
    h2 hv = *(const h2*)(vrow + 2 * q);
    H8 u0; u0.v = *(const h8v*)(Pp + q * 16);
    H8 u1; u1.v = *(const h8v*)(Pp + q * 16 + 8);
#pragma unroll
    for (int j = 0; j < 4; j++) {
      acc[j]     = fdot2(hv, u0.p[j], acc[j]);
      acc[4 + j] = fdot2(hv, u1.p[j], acc[4 + j]);
    }
  }
}

__global__ __launch_bounds__(BD, 4) void attn_lstm_persistent(
    const float* __restrict__ x, const float* __restrict__ ctx,
    const float* __restrict__ W, const float* __restrict__ V,
    const float* __restrict__ U, const float* __restrict__ bias,
    const float* __restrict__ Wh, const float* __restrict__ Wc,
    const float* __restrict__ batt, const float* __restrict__ wprj,
    float* __restrict__ out, float* __restrict__ ws) {
  __shared__ __align__(16) unsigned char smem[63136];
  h16*   haux  = (h16*)smem;                    // 32 x 514 h16 = 32896 B
  float* red   = (float*)(smem + 32896);        // 5120 f32 = 20480 B
  float* hUk   = (float*)(smem + 53376);        // [8 c][32 b]
  float* xwk   = (float*)(smem + 54400);        // [2][8 c][32 b]
  float* hattp = (float*)(smem + 56448);        // 512
  float* zinvs = (float*)(smem + 58496);        // 32
  float* wprjs = (float*)(smem + 59008);        // 512
  float* pre   = (float*)(smem + 61056);        // [8 c][32 b]
  float* bias8 = (float*)(smem + 62080);        // 8
  h16*   hb2   = (h16*)(smem + 62112);          // 512 h16 (16B aligned)

  const int w = blockIdx.x;
  const int t = threadIdx.x;
  int*   flags = (int*)(ws + OFF_FLAGS_F);
  int*   rel   = (int*)(ws + OFF_REL_F);
  float* sexpr = ws + OFF_SEXPR;
  h16*   hb    = (h16*)(ws + OFF_H16_F);
  h16*   x16   = hb + HO_X16;
  h16*   att16 = hb + HO_ATT;
  h16*   hring = hb + HO_HRING;
  h16*   ctx16p= hb + HO_CTX16;
  h16*   wh16  = hb + HO_WH16;
  h16*   packA = hb + HO_PACK;
  h16*   ctxv  = hb + HO_CTXV;
  const h16* mypack = packA + (size_t)w * PACKSZ;
  const h16* PW  = mypack;            // x@W cols
  const h16* PU  = mypack + 4096;     // h@U cols
  const h16* PV  = mypack + 8192;     // ctx@V cols (setup only)
  const h16* myctxv = ctxv + (size_t)w * 32768;  // [128 l][32 b][8 cc]
  int gen = 0;

  const bool isScore = (w >= 32 && w < 64);
  const int b2 = w - 32;              // score batch for score-WGs

  float c_reg = 0.f;                  // t<64 own c[b = t&31][2w + (t>>5)]

  // ================= setup =================
  // pack W/U/V transposed-cooperatively: WG w owns k-pair kp=w (rows 2w,2w+1)
  {
    const int kp = w;
    const float* srcs[3] = {W, U, V};
#pragma unroll
    for (int mat = 0; mat < 3; mat++) {
      const float* s0 = srcs[mat] + (size_t)(2 * kp) * KK4;
      const float* s1 = s0 + KK4;
#pragma unroll
      for (int rep = 0; rep < 2; rep++) {
        int col = t + rep * 1024;
        float v0 = s0[col], v1 = s1[col];
        int wo = (col & 511) >> 1;
        int cc = (col & 1) + ((col >> 9) << 1);
        H2U pu; pu.h = h2{(h16)v0, (h16)v1};
        cstoreu((unsigned*)(packA + (size_t)wo * PACKSZ + mat * 4096 + kp * 16 + cc * 2),
                pu.u);
      }
    }
    // Wh16 pack: [kpg][a][slot] h2, kpg = kp>>2, slot = kp&3
    if (t < 512) {
      int a = t;
      float v0 = Wh[(size_t)(2 * kp) * DD + a];
      float v1 = Wh[(size_t)(2 * kp + 1) * DD + a];
      H2U pu; pu.h = h2{(h16)v0, (h16)v1};
      cstoreu((unsigned*)(wh16 + 2 * ((size_t)(kp >> 2) * 2048 + (size_t)a * 4 + (kp & 3))),
              pu.u);
    }
  }
  // x16 = fp16(x), layout [st][ch][b][16]
  {
    const int b = w >> 3;
    const int st = (w & 7) * 32 + (t >> 5);
    const int ch = t & 31;
    const float* src = x + ((size_t)b * TSTEPS + st) * DD + ch * 16;
    h16* dst = x16 + (size_t)st * 16384 + (size_t)ch * 512 + (size_t)b * 16;
#pragma unroll
    for (int q = 0; q < 4; q++) {
      float4 v = *(const float4*)(src + 4 * q);
      H2U lo; lo.h = h2{(h16)v.x, (h16)v.y};
      H2U hi; hi.h = h2{(h16)v.z, (h16)v.w};
      unsigned long long pk = (unsigned long long)lo.u | ((unsigned long long)hi.u << 32);
      cstoreu8((unsigned long long*)(dst + 4 * q), pk);
    }
  }
  // ctx16 = fp16(ctx), layout [ch][r][16]
  {
    const int r = w * 16 + (t >> 6);
    const int c0 = (t & 63) * 8;
    const float* src = ctx + (size_t)r * DD + c0;
    h16* dst = ctx16p + (size_t)(c0 >> 4) * 65536 + (size_t)r * 16 + (c0 & 15);
#pragma unroll
    for (int q = 0; q < 2; q++) {
      float4 v = *(const float4*)(src + 4 * q);
      H2U lo; lo.h = h2{(h16)v.x, (h16)v.y};
      H2U hi; hi.h = h2{(h16)v.z, (h16)v.w};
      unsigned long long pk = (unsigned long long)lo.u | ((unsigned long long)hi.u << 32);
      cstoreu8((unsigned long long*)(dst + 4 * q), pk);
    }
  }
  // att16 = fp16(ctx @ Wc + b_att), 16 rows per WG (rows = b*128+l)
  {
    float* fbuf = (float*)smem;                   // 32 KB staging
    const int r0 = w * 16;
#pragma unroll
    for (int i = 0; i < 2; i++) {
      int idx4 = i * BD + t;
      int row = idx4 >> 7, c4 = idx4 & 127;
      ((float4*)fbuf)[idx4] = ((const float4*)(ctx + (size_t)(r0 + row) * DD))[c4];
    }
    __syncthreads();
    const int a0 = t & 511, rh = t >> 9;
    float acc[8];
#pragma unroll
    for (int r = 0; r < 8; r++) acc[r] = 0.f;
    for (int cc = 0; cc < DD; cc++) {
      float wv = Wc[(size_t)cc * DD + a0];
#pragma unroll
      for (int r = 0; r < 8; r++)
        acc[r] += fbuf[(8 * rh + r) * DD + cc] * wv;
    }
    const float ba = batt[a0];
    for (int r = 0; r < 8; r++)
      cstores(att16 + (size_t)(r0 + 8 * rh + r) * DD + a0, (h16)(acc[r] + ba));
    __syncthreads();
  }
  // stage wprj + bias8
  if (t < 512) wprjs[t] = wprj[t];
  if (t < 8) bias8[t] = bias[2 * w + (t & 1) + (t >> 1) * 512];
  gsync(flags, rel, w, gen);

  // ctxV = (ctx @ V) for my 8 cols, packed [l][b][cc] fp16 (self-written/read)
  {
    h16* myctxvw = ctxv + (size_t)w * 32768;
    for (int it = 0; it < 128; it++) {
      const int r0 = it * 32;  // bl-rows r0..r0+31  (r = b*128 + l)
      {
        const int bb = t & 31, ch = t >> 5;
        const uint4* sp = (const uint4*)(ctx16p + (size_t)ch * 65536 + (size_t)(r0 + bb) * 16);
        uint4 v0 = sp[0], v1 = sp[1];
        unsigned* dp = (unsigned*)(haux + bb * 514 + ch * 16);
        dp[0] = v0.x; dp[1] = v0.y; dp[2] = v0.z; dp[3] = v0.w;
        dp[4] = v1.x; dp[5] = v1.y; dp[6] = v1.z; dp[7] = v1.w;
      }
      __syncthreads();
      {
        const int lr = t & 31, s = t >> 5;
        float acc[8] = {0.f,0.f,0.f,0.f,0.f,0.f,0.f,0.f};
        mac8(haux, PV, s, lr, acc);
#pragma unroll
        for (int c = 0; c < 8; c++) acc[c] += __shfl_xor(acc[c], 32);
        if ((t & 32) == 0) {
          int s2 = t >> 6;
#pragma unroll
          for (int c = 0; c < 8; c++) red[s2 * 256 + c * 32 + lr] = acc[c];
        }
      }
      __syncthreads();
      if (t < 256) {
        float sm = 0.f;
#pragma unroll
        for (int j2 = 0; j2 < 16; j2++) sm += red[j2 * 256 + t];
        int r = r0 + (t & 31);
        myctxvw[((size_t)(r & 127) * 32 + (r >> 7)) * 8 + (t >> 5)] = (h16)sm;
      }
      __syncthreads();
    }
  }

  // xw for step 0
  {
    const int bb = t & 31, ch = t >> 5;
    const uint4* sp = (const uint4*)(x16 + (size_t)ch * 512 + (size_t)bb * 16);
    uint4 v0 = sp[0], v1 = sp[1];
    unsigned* dp = (unsigned*)(haux + bb * 514 + ch * 16);
    dp[0] = v0.x; dp[1] = v0.y; dp[2] = v0.z; dp[3] = v0.w;
    dp[4] = v1.x; dp[5] = v1.y; dp[6] = v1.z; dp[7] = v1.w;
    __syncthreads();
    const int b = t & 31, s = t >> 5;
    float acc[8] = {0.f,0.f,0.f,0.f,0.f,0.f,0.f,0.f};
    mac8(haux, PW, s, b, acc);
#pragma unroll
    for (int c = 0; c < 8; c++) acc[c] += __shfl_xor(acc[c], 32);
    if ((t & 32) == 0) {
      int s2 = t >> 6;
#pragma unroll
      for (int c = 0; c < 8; c++) red[s2 * 256 + c * 32 + b] = acc[c];
    }
    __syncthreads();
    if (t < 256) {
      float sm = 0.f;
#pragma unroll
      for (int j2 = 0; j2 < 16; j2++) sm += red[j2 * 256 + t];
      xwk[t] = sm;
    }
    __syncthreads();
  }

  // ================= recurrence: 2 grid barriers/step =================
  for (int step = 0; step < TSTEPS; step++) {
    // ---- A: hU for all WGs; score-WGs also full hatt + all 128 scores ----
    {
      const int bb = t & 31, ch = t >> 5;
      uint4 v0 = make_uint4(0, 0, 0, 0), v1 = make_uint4(0, 0, 0, 0);
      if (step > 0) {
        const uint4* sp = (const uint4*)(hring + (size_t)(step - 1) * 16384 +
                                         (size_t)ch * 512 + (size_t)bb * 16);
        v0 = sp[0]; v1 = sp[1];
      }
      unsigned* dp = (unsigned*)(haux + bb * 514 + ch * 16);
      dp[0] = v0.x; dp[1] = v0.y; dp[2] = v0.z; dp[3] = v0.w;
      dp[4] = v1.x; dp[5] = v1.y; dp[6] = v1.z; dp[7] = v1.w;
      if (isScore && t < 64) {
        uint4 z = make_uint4(0, 0, 0, 0);
        if (step > 0)
          z = *(const uint4*)(hring + (size_t)(step - 1) * 16384 +
                              (size_t)(t >> 1) * 512 + (size_t)b2 * 16 + (size_t)(t & 1) * 8);
        *(uint4*)(hb2 + t * 8) = z;
      }
      __syncthreads();
      // hU partials (all WGs)
      {
        const int b = t & 31, s = t >> 5;
        float acc[8] = {0.f,0.f,0.f,0.f,0.f,0.f,0.f,0.f};
        mac8(haux, PU, s, b, acc);
#pragma unroll
        for (int c = 0; c < 8; c++) acc[c] += __shfl_xor(acc[c], 32);
        if ((t & 32) == 0) {
          int s2 = t >> 6;
#pragma unroll
          for (int c = 0; c < 8; c++) red[s2 * 256 + c * 32 + b] = acc[c];
        }
      }
      if (isScore) {
        // hatt partials: a = t&511, halves of k
        const int a = t & 511, half = t >> 9;
        float p = 0.f;
        const h8v* hv8 = (const h8v*)hb2;
#pragma unroll 4
        for (int kg = 0; kg < 32; kg++) {
          int kpg = half * 32 + kg;
          H8 hh; hh.v = hv8[kpg];
          H8 wv; wv.v = *(const h8v*)(wh16 + ((size_t)kpg * 512 + a) * 8);
          p = fdot2(hh.p[0], wv.p[0], p);
          p = fdot2(hh.p[1], wv.p[1], p);
          p = fdot2(hh.p[2], wv.p[2], p);
          p = fdot2(hh.p[3], wv.p[3], p);
        }
        red[4096 + t] = p;
      }
      __syncthreads();
      if (t < 256) {
        float sm = 0.f;
#pragma unroll
        for (int j2 = 0; j2 < 16; j2++) sm += red[j2 * 256 + t];
        hUk[t] = sm;
      } else if (isScore && t < 768) {
        int a = t - 256;
        hattp[a] = red[4096 + a] + red[4096 + 512 + a];
      }
      if (isScore) {
        __syncthreads();
        // all 128 scores for batch b2: l = t>>3, 8 lanes per l
        const int l = t >> 3, as = t & 7;
        const h16* arow = att16 + (size_t)(b2 * LC + l) * DD;
        float p = 0.f;
#pragma unroll 8
        for (int j2 = 0; j2 < 64; j2++) {
          int a = as + 8 * j2;
          p += ftanh((float)arow[a] + hattp[a]) * wprjs[a];
        }
        p += __shfl_xor(p, 1); p += __shfl_xor(p, 2); p += __shfl_xor(p, 4);
        if (as == 0) cstoref(sexpr + (size_t)b2 * LC + l, __expf(p));
      }
    }
    gsync(flags, rel, w, gen);

    // ---- B: softmax(all b) + exp@ctxV + preact + gates; publish h; xw prefetch ----
    {
      float* sexa = (float*)haux;              // [128 l][33] padded transpose
      {
        const int b = t & 31, l04 = 4 * (t >> 5);
        float e0 = cloadf(sexpr + (size_t)b * LC + l04 + 0);
        float e1 = cloadf(sexpr + (size_t)b * LC + l04 + 1);
        float e2 = cloadf(sexpr + (size_t)b * LC + l04 + 2);
        float e3 = cloadf(sexpr + (size_t)b * LC + l04 + 3);
        sexa[(l04 + 0) * 33 + b] = e0;
        sexa[(l04 + 1) * 33 + b] = e1;
        sexa[(l04 + 2) * 33 + b] = e2;
        sexa[(l04 + 3) * 33 + b] = e3;
      }
      __syncthreads();
      if (t < 32) {
        float z = 0.f;
#pragma unroll
        for (int l = 0; l < 128; l++) z += sexa[l * 33 + t];
        zinvs[t] = rcp_fast(z);
      }
      {
        const int b = t & 31, s = t >> 5;
        float acc[8] = {0.f,0.f,0.f,0.f,0.f,0.f,0.f,0.f};
#pragma unroll
        for (int j = 0; j < 4; j++) {
          const int l = 4 * s + j;
          const float e = sexa[l * 33 + b];
          H8 u; u.v = *(const h8v*)(myctxv + ((size_t)l * 32 + b) * 8);
#pragma unroll
          for (int c = 0; c < 8; c++) acc[c] += e * (float)u.v[c];
        }
#pragma unroll
        for (int c = 0; c < 8; c++) acc[c] += __shfl_xor(acc[c], 32);
        if ((t & 32) == 0) {
          int s2 = t >> 6;
#pragma unroll
          for (int c = 0; c < 8; c++) red[s2 * 256 + c * 32 + b] = acc[c];
        }
      }
      __syncthreads();
      if (t < 256) {
        float sm = 0.f;
#pragma unroll
        for (int j2 = 0; j2 < 16; j2++) sm += red[j2 * 256 + t];
        pre[t] = sm * zinvs[t & 31] + hUk[t] + xwk[(step & 1) * 256 + t] + bias8[t >> 5];
      }
      __syncthreads();
      if (t < 64) {
        const int b3 = t & 31, dd = t >> 5;
        float pi = pre[(0 + dd) * 32 + b3];
        float pf = pre[(2 + dd) * 32 + b3];
        float po = pre[(4 + dd) * 32 + b3];
        float pg = pre[(6 + dd) * 32 + b3];
        float ig = fsig(pi), fg = fsig(pf), og = fsig(po), gg = ftanh(pg);
        float cn = fg * c_reg + ig * gg;
        c_reg = cn;
        float hn = og * ftanh(cn);
        out[((size_t)b3 * TSTEPS + step) * DD + 2 * w + dd] = hn;
        float hn2 = __shfl_xor(hn, 32);
        if (t < 32) {
          H2U pu; pu.h = h2{(h16)hn, (h16)hn2};
          cstoreu((unsigned*)(hring + (size_t)step * 16384 + (size_t)(w >> 3) * 512 +
                              (size_t)t * 16 + 2 * (w & 7)),
                  pu.u);
        }
      }
      if (step + 1 < TSTEPS) {
        const int bb = t & 31, ch = t >> 5;
        const uint4* sp = (const uint4*)(x16 + (size_t)(step + 1) * 16384 +
                                         (size_t)ch * 512 + (size_t)bb * 16);
        uint4 v0 = sp[0], v1 = sp[1];
        unsigned* dp = (unsigned*)(haux + bb * 514 + ch * 16);
        dp[0] = v0.x; dp[1] = v0.y; dp[2] = v0.z; dp[3] = v0.w;
        dp[4] = v1.x; dp[5] = v1.y; dp[6] = v1.z; dp[7] = v1.w;
        __syncthreads();
        const int b = t & 31, s = t >> 5;
        float acc[8] = {0.f,0.f,0.f,0.f,0.f,0.f,0.f,0.f};
        mac8(haux, PW, s, b, acc);
#pragma unroll
        for (int c = 0; c < 8; c++) acc[c] += __shfl_xor(acc[c], 32);
        if ((t & 32) == 0) {
          int s2 = t >> 6;
#pragma unroll
          for (int c = 0; c < 8; c++) red[s2 * 256 + c * 32 + b] = acc[c];
        }
        __syncthreads();
        if (t < 256) {
          float sm = 0.f;
#pragma unroll
          for (int j2 = 0; j2 < 16; j2++) sm += red[j2 * 256 + t];
          xwk[((step + 1) & 1) * 256 + t] = sm;
        }
      }
    }
    gsync(flags, rel, w, gen);
  }
}

extern "C" void kernel_launch(void* const* d_in, const int* in_sizes, int n_in,
                              void* d_out, int out_size, void* d_ws, size_t ws_size,
                              hipStream_t stream) {
  (void)in_sizes; (void)n_in; (void)out_size; (void)ws_size;
  const float* x    = (const float*)d_in[0];
  const float* ctx  = (const float*)d_in[1];
  const float* W    = (const float*)d_in[2];
  const float* V    = (const float*)d_in[3];
  const float* U    = (const float*)d_in[4];
  const float* b    = (const float*)d_in[5];
  const float* Wh   = (const float*)d_in[6];
  const float* Wc   = (const float*)d_in[7];
  const float* batt = (const float*)d_in[8];
  const float* wprj = (const float*)d_in[9];

  hipMemsetAsync(d_ws, 0, (8192 + 256) * sizeof(int), stream);

  hipLaunchKernelGGL(attn_lstm_persistent, dim3(GD), dim3(BD), 0, stream,
                     x, ctx, W, V, U, b, Wh, Wc, batt, wprj,
                     (float*)d_out, (float*)d_ws);
}

// Round 4
// 3294.802 us; speedup vs baseline: 2.0822x; 2.0822x over previous
//
#include <hip/hip_runtime.h>
#include <hip/hip_fp16.h>

#define GD 256   // 1 WG per CU, persistent
#define BD 1024  // 16 waves

constexpr int TSTEPS = 256;
constexpr int DD = 512;
constexpr int LC = 128;

// ---- ws float offsets ----
constexpr size_t OFF_FLAGS_F = 0;       // grid flags: 256 lines (stride 32 ints)
constexpr size_t OFF_REL_F   = 8192;    // 8 release lines
constexpr size_t OFF_GFLG_F  = 8448;    // group flags [32 b][8 oct][32 ints]
constexpr size_t OFF_SEXPR   = 16640;   // [32][128] f32 exp scores
constexpr size_t OFF_HATTX   = 20736;   // [32][512] f32 hatt exchange
constexpr size_t OFF_H16_F   = 37120;   // h16 base
// ---- h16-unit offsets ----
constexpr size_t HO_HRING = 0;          // [32 b][256 st][512] h
constexpr size_t HO_ATT   = 4194304;    // [4096 r][512] attc
constexpr size_t HO_U16   = 6291456;    // [8 oct][256 kp][256 cc][2]
constexpr size_t HO_WH16  = 7340032;    // [8 oct][256 kp][64 a][2]
constexpr size_t HO_CTXV  = 7602176;    // [32 b][8 oct][128 l][256 cc]
constexpr size_t HO_XW    = 15990784;   // [32 b][8 oct][256 st][256 cc]

typedef _Float16 h16;
typedef _Float16 h2  __attribute__((ext_vector_type(2)));
typedef _Float16 h8v __attribute__((ext_vector_type(8)));
union H8  { h8v v; h2 p[4]; };
union H2U { h2 h; unsigned u; };
union HSU { h16 h; unsigned short u; };

__device__ __forceinline__ float rcp_fast(float x) { return __builtin_amdgcn_rcpf(x); }
__device__ __forceinline__ float ftanh(float x) {
  float e = __expf(2.0f * x);
  return 1.0f - 2.0f * rcp_fast(e + 1.0f);
}
__device__ __forceinline__ float fsig(float x) { return rcp_fast(1.0f + __expf(-x)); }
__device__ __forceinline__ float fdot2(h2 a, h2 b, float c) {
  return __builtin_amdgcn_fdot2(a, b, c, false);
}

__device__ __forceinline__ float cloadf(const float* p) {
  return __hip_atomic_load(p, __ATOMIC_RELAXED, __HIP_MEMORY_SCOPE_AGENT);
}
__device__ __forceinline__ void cstoref(float* p, float v) {
  __hip_atomic_store(p, v, __ATOMIC_RELAXED, __HIP_MEMORY_SCOPE_AGENT);
}
__device__ __forceinline__ void cstoreu(unsigned* p, unsigned v) {
  __hip_atomic_store(p, v, __ATOMIC_RELAXED, __HIP_MEMORY_SCOPE_AGENT);
}
__device__ __forceinline__ void cstoreu8(unsigned long long* p, unsigned long long v) {
  __hip_atomic_store(p, v, __ATOMIC_RELAXED, __HIP_MEMORY_SCOPE_AGENT);
}
__device__ __forceinline__ void cstores(h16* p, h16 v) {
  HSU s; s.h = v;
  __hip_atomic_store((unsigned short*)p, s.u, __ATOMIC_RELAXED,
                     __HIP_MEMORY_SCOPE_AGENT);
}

// grid barrier (setup only)
__device__ __forceinline__ void gsync(int* flags, int* rel, int w, int& gen) {
  __syncthreads();
  gen++;
  const int t = threadIdx.x;
  if (w == 0) {
    if (t < 64) {
      if (t == 0)
        __hip_atomic_store(flags, gen, __ATOMIC_RELAXED, __HIP_MEMORY_SCOPE_AGENT);
      for (;;) {
        int m = gen;
#pragma unroll
        for (int i = 0; i < 4; i++) {
          int v = __hip_atomic_load(flags + (t + i * 64) * 32,
                                    __ATOMIC_RELAXED, __HIP_MEMORY_SCOPE_AGENT);
          m = (v < m) ? v : m;
        }
        if (__all(m >= gen)) break;
      }
      if (t == 0) {
#pragma unroll
        for (int i = 0; i < 8; i++)
          __hip_atomic_store(rel + i * 32, gen, __ATOMIC_RELAXED,
                             __HIP_MEMORY_SCOPE_AGENT);
      }
    }
    asm volatile("" ::: "memory");
  } else {
    if (t == 0) {
      __hip_atomic_store(flags + w * 32, gen, __ATOMIC_RELAXED,
                         __HIP_MEMORY_SCOPE_AGENT);
      const int* r = rel + (w & 7) * 32;
      while (__hip_atomic_load(r, __ATOMIC_RELAXED, __HIP_MEMORY_SCOPE_AGENT) < gen)
        __builtin_amdgcn_s_sleep(1);
    }
    asm volatile("" ::: "memory");
  }
  __syncthreads();
}

// 8-WG group barrier: symmetric flag + poll (no master round-trip)
__device__ __forceinline__ void gbar(int* gf, int oct, int& sg) {
  __syncthreads();
  sg++;
  const int t = threadIdx.x;
  if (t < 64) {
    if (t == 0)
      __hip_atomic_store(gf + oct * 32, sg, __ATOMIC_RELAXED,
                         __HIP_MEMORY_SCOPE_AGENT);
    for (;;) {
      int v = sg;
      if (t < 8)
        v = __hip_atomic_load(gf + t * 32, __ATOMIC_RELAXED,
                              __HIP_MEMORY_SCOPE_AGENT);
      if (__all(v >= sg)) break;
      __builtin_amdgcn_s_sleep(1);
    }
  }
  asm volatile("" ::: "memory");
  __syncthreads();
}

__global__ __launch_bounds__(BD, 4) void attn_lstm_persistent(
    const float* __restrict__ x, const float* __restrict__ ctx,
    const float* __restrict__ W, const float* __restrict__ V,
    const float* __restrict__ U, const float* __restrict__ bias,
    const float* __restrict__ Wh, const float* __restrict__ Wc,
    const float* __restrict__ batt, const float* __restrict__ wprj,
    float* __restrict__ out, float* __restrict__ ws) {
  __shared__ __align__(16) unsigned char smem[56840];
  float* red    = (float*)(smem + 32768);  // 4096 f32
  float* hUk    = (float*)(smem + 49152);  // 256
  float* pre    = (float*)(smem + 50176);  // 256
  float* hattFT = (float*)(smem + 51200);  // 512 (transposed [j][alane])
  float* sl     = (float*)(smem + 53248);  // 128
  float* wpT    = (float*)(smem + 53760);  // 512 (transposed)
  float* biasS  = (float*)(smem + 55808);  // 256
  float* zinvS  = (float*)(smem + 56832);  // 1

  const int w = blockIdx.x;
  const int t = threadIdx.x;
  const int b = w >> 3;    // batch owned by this group
  const int oct = w & 7;   // dim-slice [64*oct, 64*oct+64)

  int* flags = (int*)(ws + OFF_FLAGS_F);
  int* rel   = (int*)(ws + OFF_REL_F);
  int* gfl   = (int*)(ws + OFF_GFLG_F) + b * 256;
  float* sexpr = ws + OFF_SEXPR;
  float* hattX = ws + OFF_HATTX;
  h16* hb16   = (h16*)(ws + OFF_H16_F);
  h16* hringB = hb16 + HO_HRING;
  h16* att16  = hb16 + HO_ATT;
  h2*  U2     = (h2*)(hb16 + HO_U16) + (size_t)oct * 65536;
  h2*  Wh2    = (h2*)(hb16 + HO_WH16) + (size_t)oct * 16384;
  h16* ctxVp  = hb16 + HO_CTXV;
  h16* xw16   = hb16 + HO_XW;

  int gen = 0, sg = 0;
  float c_reg = 0.f;   // t<64: cell state c[b][64*oct + t]

  // ================= setup =================
  // 1) pack U16p/Wh16p: WG w owns k-pair kp = w (rows 2w, 2w+1)
  {
    const int kp = w;
    {
      const float* r0p = U + (size_t)(2 * kp) * 2048;
      const float* r1p = r0p + 2048;
      const int col0 = 2 * t;
      float u00 = r0p[col0], u01 = r0p[col0 + 1];
      float u10 = r1p[col0], u11 = r1p[col0 + 1];
      int oc  = (col0 & 511) >> 6;
      int cc0 = ((col0 >> 9) << 6) | (col0 & 63);
      H2U p0; p0.h = h2{(h16)u00, (h16)u10};
      H2U p1; p1.h = h2{(h16)u01, (h16)u11};
      unsigned long long pk =
          (unsigned long long)p0.u | ((unsigned long long)p1.u << 32);
      cstoreu8((unsigned long long*)((h2*)(hb16 + HO_U16) +
                                     (size_t)oc * 65536 + (size_t)kp * 256 + cc0),
               pk);
    }
    if (t < 512) {
      float w0 = Wh[(size_t)(2 * kp) * DD + t];
      float w1 = Wh[(size_t)(2 * kp + 1) * DD + t];
      H2U pu; pu.h = h2{(h16)w0, (h16)w1};
      cstoreu((unsigned*)((h2*)(hb16 + HO_WH16) + (size_t)(t >> 6) * 16384 +
                          (size_t)kp * 64 + (t & 63)),
              pu.u);
    }
  }
  // 2) attc16 = fp16(ctx @ Wc + b_att): 16 rows per WG
  {
    float* fbuf = (float*)smem;  // 32 KB
    const int r0 = w * 16;
#pragma unroll
    for (int i = 0; i < 2; i++) {
      int idx4 = i * BD + t;
      int row = idx4 >> 7, c4 = idx4 & 127;
      ((float4*)fbuf)[idx4] = ((const float4*)(ctx + (size_t)(r0 + row) * DD))[c4];
    }
    __syncthreads();
    const int a0 = t & 511, rh = t >> 9;
    float acc[8];
#pragma unroll
    for (int r = 0; r < 8; r++) acc[r] = 0.f;
    for (int cc = 0; cc < DD; cc++) {
      float wv = Wc[(size_t)cc * DD + a0];
#pragma unroll
      for (int r = 0; r < 8; r++)
        acc[r] += fbuf[(8 * rh + r) * DD + cc] * wv;
    }
    const float ba = batt[a0];
    for (int r = 0; r < 8; r++)
      cstores(att16 + (size_t)(r0 + 8 * rh + r) * DD + a0, (h16)(acc[r] + ba));
    __syncthreads();
  }
  // 3) stage wpT (transposed) + biasS
  if (t < 512) wpT[((t & 7) << 6) | (t >> 3)] = wprj[t];
  if (t < 256) biasS[t] = bias[(size_t)(t >> 6) * 512 + 64 * oct + (t & 63)];

  // 4) xw16[b][oct][st][cc] = fp16( x[b] @ W[:, cols(oct)] ), 8 chunks of 32 st
  {
    h2* xstage = (h2*)smem;  // [32][256]
    for (int chk = 0; chk < 8; chk++) {
      const int st0 = chk * 32;
      {
        const int row = t >> 5, seg = t & 31;
        const float* src = x + ((size_t)b * TSTEPS + st0 + row) * DD + seg * 16;
        h2* dst = xstage + row * 256 + seg * 8;
#pragma unroll
        for (int q = 0; q < 4; q++) {
          float4 v = *(const float4*)(src + 4 * q);
          dst[2 * q]     = h2{(h16)v.x, (h16)v.y};
          dst[2 * q + 1] = h2{(h16)v.z, (h16)v.w};
        }
      }
      __syncthreads();
      const int cc = t & 255, sq = t >> 8;
      const int col = ((cc >> 6) << 9) + 64 * oct + (cc & 63);
      float acc[8];
#pragma unroll
      for (int j = 0; j < 8; j++) acc[j] = 0.f;
#pragma unroll 2
      for (int kp = 0; kp < 256; kp++) {
        float w0 = W[(size_t)(2 * kp) * 2048 + col];
        float w1 = W[(size_t)(2 * kp + 1) * 2048 + col];
        h2 wp = h2{(h16)w0, (h16)w1};
#pragma unroll
        for (int j = 0; j < 8; j++)
          acc[j] = fdot2(xstage[(sq * 8 + j) * 256 + kp], wp, acc[j]);
      }
#pragma unroll
      for (int j = 0; j < 8; j++)
        cstores(xw16 + (((size_t)(b * 8 + oct) * 256) + st0 + sq * 8 + j) * 256 + cc,
                (h16)acc[j]);
      __syncthreads();
    }
  }
  // 5) ctxVp[b][oct][l][cc] = fp16( ctx[b] @ V[:, cols(oct)] ), 4 chunks of 32 l
  {
    h2* xstage = (h2*)smem;
    for (int chk = 0; chk < 4; chk++) {
      const int l0 = chk * 32;
      {
        const int row = t >> 5, seg = t & 31;
        const float* src = ctx + ((size_t)b * LC + l0 + row) * DD + seg * 16;
        h2* dst = xstage + row * 256 + seg * 8;
#pragma unroll
        for (int q = 0; q < 4; q++) {
          float4 v = *(const float4*)(src + 4 * q);
          dst[2 * q]     = h2{(h16)v.x, (h16)v.y};
          dst[2 * q + 1] = h2{(h16)v.z, (h16)v.w};
        }
      }
      __syncthreads();
      const int cc = t & 255, lq = t >> 8;
      const int col = ((cc >> 6) << 9) + 64 * oct + (cc & 63);
      float acc[8];
#pragma unroll
      for (int j = 0; j < 8; j++) acc[j] = 0.f;
#pragma unroll 2
      for (int kp = 0; kp < 256; kp++) {
        float v0 = V[(size_t)(2 * kp) * 2048 + col];
        float v1 = V[(size_t)(2 * kp + 1) * 2048 + col];
        h2 vp = h2{(h16)v0, (h16)v1};
#pragma unroll
        for (int j = 0; j < 8; j++)
          acc[j] = fdot2(xstage[(lq * 8 + j) * 256 + kp], vp, acc[j]);
      }
#pragma unroll
      for (int j = 0; j < 8; j++)
        cstores(ctxVp + (((size_t)(b * 8 + oct) * 128) + l0 + lq * 8 + j) * 256 + cc,
                (h16)acc[j]);
      __syncthreads();
    }
  }
  gsync(flags, rel, w, gen);

  // ================= recurrence: 3 group barriers/step, NO grid barrier ======
  for (int step = 0; step < TSTEPS; step++) {
    H8 pv0, pv1, pv2, pv3;
    float xwv = 0.f;

    // ---- Phase 1: stage h[b]; hU (256 cc) + hatt (64 a) ----
    {
      h2* hLDS = (h2*)smem;  // 256 h2 = h[b]
      if (t < 256) {
        unsigned hv = 0;
        if (step > 0)
          hv = *(const unsigned*)(hringB + ((size_t)b * TSTEPS + step - 1) * DD +
                                  2 * t);
        ((unsigned*)hLDS)[t] = hv;
      }
      __syncthreads();
      const int cc = t & 255, kq = t >> 8;
      const int kp0 = kq * 64;
      float f0 = 0.f, f1 = 0.f;
#pragma unroll 4
      for (int i = 0; i < 64; i += 2) {
        f0 = fdot2(hLDS[kp0 + i],     U2[(size_t)(kp0 + i) * 256 + cc],     f0);
        f1 = fdot2(hLDS[kp0 + i + 1], U2[(size_t)(kp0 + i + 1) * 256 + cc], f1);
      }
      red[kq * 256 + cc] = f0 + f1;
      if (t < 512) {
        const int a = t & 63, kg = t >> 6;
        const int kh0 = kg * 32;
        float ha = 0.f;
#pragma unroll 4
        for (int i = 0; i < 32; i++)
          ha = fdot2(hLDS[kh0 + i], Wh2[(size_t)(kh0 + i) * 64 + a], ha);
        red[1024 + kg * 64 + a] = ha;
      }
      __syncthreads();
      if (t < 256) {
        hUk[t] = red[t] + red[256 + t] + red[512 + t] + red[768 + t];
      } else if (t < 320) {
        int a = t - 256;
        float ha = 0.f;
#pragma unroll
        for (int kg = 0; kg < 8; kg++) ha += red[1024 + kg * 64 + a];
        cstoref(hattX + (size_t)b * DD + 64 * oct + a, ha);
      }
    }
    gbar(gfl, oct, sg);

    // ---- Phase 2: scores for my 16 l's; prefetch ctxV/xw into regs ----
    {
      if (t < 512)
        hattFT[((t & 7) << 6) | (t >> 3)] = cloadf(hattX + (size_t)b * DD + t);
      __syncthreads();
      const int l = t >> 6, alane = t & 63;
      H8 av;
      av.v = *(const h8v*)(att16 + (size_t)(b * LC + 16 * oct + l) * DD + alane * 8);
      float p = 0.f;
#pragma unroll
      for (int j = 0; j < 8; j++)
        p += ftanh((float)av.v[j] + hattFT[j * 64 + alane]) * wpT[j * 64 + alane];
      p += __shfl_xor(p, 1);  p += __shfl_xor(p, 2);  p += __shfl_xor(p, 4);
      p += __shfl_xor(p, 8);  p += __shfl_xor(p, 16); p += __shfl_xor(p, 32);
      if (alane == 0)
        cstoref(sexpr + (size_t)b * LC + 16 * oct + l, __expf(p));
      // prefetch (read-only setup data; safe across the barrier)
      const int ccg = t & 31, lq = t >> 5;
      const h16* cvb = ctxVp + ((size_t)(b * 8 + oct) * 128) * 256 + ccg * 8;
      pv0.v = *(const h8v*)(cvb + (lq * 4 + 0) * 256);
      pv1.v = *(const h8v*)(cvb + (lq * 4 + 1) * 256);
      pv2.v = *(const h8v*)(cvb + (lq * 4 + 2) * 256);
      pv3.v = *(const h8v*)(cvb + (lq * 4 + 3) * 256);
      if (t < 256)
        xwv = (float)xw16[(((size_t)(b * 8 + oct) * 256) + step) * 256 + t];
    }
    gbar(gfl, oct, sg);

    // ---- Phase 3: softmax Z + PV + preact + gates; publish h ----
    {
      if (t < 128) sl[t] = cloadf(sexpr + (size_t)b * LC + t);
      __syncthreads();
      if (t < 64) {
        float z = sl[t] + sl[t + 64];
        z += __shfl_xor(z, 32); z += __shfl_xor(z, 16); z += __shfl_xor(z, 8);
        z += __shfl_xor(z, 4);  z += __shfl_xor(z, 2);  z += __shfl_xor(z, 1);
        if (t == 0) *zinvS = rcp_fast(z);
      }
      const int ccg = t & 31, lq = t >> 5, w16 = t >> 6;
      float acc8[8];
#pragma unroll
      for (int j = 0; j < 8; j++) acc8[j] = 0.f;
      {
        float e0 = sl[lq * 4 + 0], e1 = sl[lq * 4 + 1];
        float e2 = sl[lq * 4 + 2], e3 = sl[lq * 4 + 3];
#pragma unroll
        for (int j = 0; j < 8; j++) {
          acc8[j] += e0 * (float)pv0.v[j];
          acc8[j] += e1 * (float)pv1.v[j];
          acc8[j] += e2 * (float)pv2.v[j];
          acc8[j] += e3 * (float)pv3.v[j];
        }
      }
#pragma unroll
      for (int j = 0; j < 8; j++) acc8[j] += __shfl_xor(acc8[j], 32);
      if ((t & 63) < 32) {
#pragma unroll
        for (int j = 0; j < 8; j++) red[w16 * 256 + ccg * 8 + j] = acc8[j];
      }
      __syncthreads();
      if (t < 256) {
        float pvs = 0.f;
#pragma unroll
        for (int k = 0; k < 16; k++) pvs += red[k * 256 + t];
        pre[t] = pvs * (*zinvS) + hUk[t] + xwv + biasS[t];
      }
      __syncthreads();
      if (t < 64) {
        const int d = t;
        float pi = pre[d], pf = pre[64 + d], po = pre[128 + d], pg = pre[192 + d];
        float ig = fsig(pi), fg = fsig(pf), og = fsig(po), gg = ftanh(pg);
        float cn = fg * c_reg + ig * gg;
        c_reg = cn;
        float hn = og * ftanh(cn);
        out[((size_t)b * TSTEPS + step) * DD + 64 * oct + d] = hn;
        cstores(hringB + ((size_t)b * TSTEPS + step) * DD + 64 * oct + d, (h16)hn);
      }
    }
    gbar(gfl, oct, sg);
  }
}

extern "C" void kernel_launch(void* const* d_in, const int* in_sizes, int n_in,
                              void* d_out, int out_size, void* d_ws, size_t ws_size,
                              hipStream_t stream) {
  (void)in_sizes; (void)n_in; (void)out_size; (void)ws_size;
  const float* x    = (const float*)d_in[0];
  const float* ctx  = (const float*)d_in[1];
  const float* W    = (const float*)d_in[2];
  const float* V    = (const float*)d_in[3];
  const float* U    = (const float*)d_in[4];
  const float* b    = (const float*)d_in[5];
  const float* Wh   = (const float*)d_in[6];
  const float* Wc   = (const float*)d_in[7];
  const float* batt = (const float*)d_in[8];
  const float* wprj = (const float*)d_in[9];

  // zero grid flags + rel + group flags
  hipMemsetAsync(d_ws, 0, (8192 + 256 + 8192) * sizeof(int), stream);

  hipLaunchKernelGGL(attn_lstm_persistent, dim3(GD), dim3(BD), 0, stream,
                     x, ctx, W, V, U, b, Wh, Wc, batt, wprj,
                     (float*)d_out, (float*)d_ws);
}

// Round 6
// 2555.152 us; speedup vs baseline: 2.6849x; 1.2895x over previous
//
#include <hip/hip_runtime.h>
#include <hip/hip_fp16.h>

#define GD 256   // 1 WG per CU, persistent
#define BD 1024  // 16 waves

constexpr int TSTEPS = 256;
constexpr int DD = 512;
constexpr int LC = 128;

// ---- ws float offsets ----
constexpr size_t OFF_FLAGS_F = 0;       // grid flags: 256 lines (stride 32 ints)
constexpr size_t OFF_REL_F   = 8192;    // 8 release lines
constexpr size_t OFF_GFLG_F  = 8448;    // group flags [32 b][8 oct][32 ints]
constexpr size_t OFF_SEXPP   = 16640;   // [32 b][8 oct][128 l] f32 partial scores
constexpr size_t OFF_H16_F   = 49408;   // h16 base
// ---- h16-unit offsets ----
constexpr size_t HO_HRING = 0;          // [32 b][256 st][512] h
constexpr size_t HO_ATT   = 4194304;    // [4096 r][512] attc
constexpr size_t HO_U16   = 6291456;    // [8 oct][256 kp][256 cc][2]
constexpr size_t HO_WH16  = 7340032;    // [8 oct][256 kp][64 a][2]
constexpr size_t HO_CTXV  = 7602176;    // [32 b][8 oct][128 l][256 cc]
constexpr size_t HO_XW    = 15990784;   // [32 b][8 oct][256 st][256 cc]

typedef _Float16 h16;
typedef _Float16 h2  __attribute__((ext_vector_type(2)));
typedef _Float16 h8v __attribute__((ext_vector_type(8)));
union H8  { h8v v; h2 p[4]; };
union H2U { h2 h; unsigned u; };
union HSU { h16 h; unsigned short u; };

__device__ __forceinline__ float rcp_fast(float x) { return __builtin_amdgcn_rcpf(x); }
__device__ __forceinline__ float ftanh(float x) {
  float e = __expf(2.0f * x);
  return 1.0f - 2.0f * rcp_fast(e + 1.0f);
}
__device__ __forceinline__ float fsig(float x) { return rcp_fast(1.0f + __expf(-x)); }
__device__ __forceinline__ float fdot2(h2 a, h2 b, float c) {
  return __builtin_amdgcn_fdot2(a, b, c, false);
}

__device__ __forceinline__ float cloadf(const float* p) {
  return __hip_atomic_load(p, __ATOMIC_RELAXED, __HIP_MEMORY_SCOPE_AGENT);
}
__device__ __forceinline__ void cstoref(float* p, float v) {
  __hip_atomic_store(p, v, __ATOMIC_RELAXED, __HIP_MEMORY_SCOPE_AGENT);
}
__device__ __forceinline__ void cstoreu(unsigned* p, unsigned v) {
  __hip_atomic_store(p, v, __ATOMIC_RELAXED, __HIP_MEMORY_SCOPE_AGENT);
}
__device__ __forceinline__ void cstoreu8(unsigned long long* p, unsigned long long v) {
  __hip_atomic_store(p, v, __ATOMIC_RELAXED, __HIP_MEMORY_SCOPE_AGENT);
}
__device__ __forceinline__ void cstores(h16* p, h16 v) {
  HSU s; s.h = v;
  __hip_atomic_store((unsigned short*)p, s.u, __ATOMIC_RELAXED,
                     __HIP_MEMORY_SCOPE_AGENT);
}

// grid barrier (setup only)
__device__ __forceinline__ void gsync(int* flags, int* rel, int w, int& gen) {
  __syncthreads();
  gen++;
  const int t = threadIdx.x;
  if (w == 0) {
    if (t < 64) {
      if (t == 0)
        __hip_atomic_store(flags, gen, __ATOMIC_RELAXED, __HIP_MEMORY_SCOPE_AGENT);
      for (;;) {
        int m = gen;
#pragma unroll
        for (int i = 0; i < 4; i++) {
          int v = __hip_atomic_load(flags + (t + i * 64) * 32,
                                    __ATOMIC_RELAXED, __HIP_MEMORY_SCOPE_AGENT);
          m = (v < m) ? v : m;
        }
        if (__all(m >= gen)) break;
      }
      if (t == 0) {
#pragma unroll
        for (int i = 0; i < 8; i++)
          __hip_atomic_store(rel + i * 32, gen, __ATOMIC_RELAXED,
                             __HIP_MEMORY_SCOPE_AGENT);
      }
    }
    asm volatile("" ::: "memory");
  } else {
    if (t == 0) {
      __hip_atomic_store(flags + w * 32, gen, __ATOMIC_RELAXED,
                         __HIP_MEMORY_SCOPE_AGENT);
      const int* r = rel + (w & 7) * 32;
      while (__hip_atomic_load(r, __ATOMIC_RELAXED, __HIP_MEMORY_SCOPE_AGENT) < gen)
        __builtin_amdgcn_s_sleep(1);
    }
    asm volatile("" ::: "memory");
  }
  __syncthreads();
}

// 8-WG group barrier: symmetric flag + poll
__device__ __forceinline__ void gbar(int* gf, int oct, int& sg) {
  __syncthreads();
  sg++;
  const int t = threadIdx.x;
  if (t < 64) {
    if (t == 0)
      __hip_atomic_store(gf + oct * 32, sg, __ATOMIC_RELAXED,
                         __HIP_MEMORY_SCOPE_AGENT);
    for (;;) {
      int v = sg;
      if (t < 8)
        v = __hip_atomic_load(gf + t * 32, __ATOMIC_RELAXED,
                              __HIP_MEMORY_SCOPE_AGENT);
      if (__all(v >= sg)) break;
      __builtin_amdgcn_s_sleep(1);
    }
  }
  asm volatile("" ::: "memory");
  __syncthreads();
}

__global__ __launch_bounds__(BD, 4) void attn_lstm_persistent(
    const float* __restrict__ x, const float* __restrict__ ctx,
    const float* __restrict__ W, const float* __restrict__ V,
    const float* __restrict__ U, const float* __restrict__ bias,
    const float* __restrict__ Wh, const float* __restrict__ Wc,
    const float* __restrict__ batt, const float* __restrict__ wprj,
    float* __restrict__ out, float* __restrict__ ws) {
  __shared__ __align__(16) unsigned char smem[58384];
  float* red    = (float*)(smem + 32768);  // 4096 f32 (P1: 1536 used; P2: 4096)
  float* hUk    = (float*)(smem + 49152);  // 256
  float* pre    = (float*)(smem + 50176);  // 256
  float* hattL  = (float*)(smem + 51200);  // 64 (local hatt a-slice)
  float* sl     = (float*)(smem + 51456);  // 128 (exp scores)
  float* spp    = (float*)(smem + 51968);  // 1024 (partial-score gather)
  float* biasS  = (float*)(smem + 56064);  // 256
  float* wprjL  = (float*)(smem + 57088);  // 64
  float* zinvS  = (float*)(smem + 57344);  // 1
  h2*    hLDS   = (h2*)(smem + 57360);     // 256 h2 = h[b]

  const int w = blockIdx.x;
  const int t = threadIdx.x;
  const int b = w >> 3;    // batch owned by this group
  const int oct = w & 7;   // dim-slice [64*oct, 64*oct+64)

  int* flags = (int*)(ws + OFF_FLAGS_F);
  int* rel   = (int*)(ws + OFF_REL_F);
  int* gfl   = (int*)(ws + OFF_GFLG_F) + b * 256;
  float* sexpP = ws + OFF_SEXPP;
  h16* hb16   = (h16*)(ws + OFF_H16_F);
  h16* hringB = hb16 + HO_HRING;
  h16* att16  = hb16 + HO_ATT;
  h2*  U2     = (h2*)(hb16 + HO_U16) + (size_t)oct * 65536;
  h2*  Wh2    = (h2*)(hb16 + HO_WH16) + (size_t)oct * 16384;
  h16* ctxVp  = hb16 + HO_CTXV;
  h16* xw16   = hb16 + HO_XW;

  int gen = 0, sg = 0;
  float c_reg = 0.f;   // t<64: cell state c[b][64*oct + t]
  H8 pv0, pv1, pv2, pv3;  // ctxV resident in registers for the whole loop

  // ================= setup =================
  // 1) pack U16p/Wh16p: WG w owns k-pair kp = w (rows 2w, 2w+1)
  {
    const int kp = w;
    {
      const float* r0p = U + (size_t)(2 * kp) * 2048;
      const float* r1p = r0p + 2048;
      const int col0 = 2 * t;
      float u00 = r0p[col0], u01 = r0p[col0 + 1];
      float u10 = r1p[col0], u11 = r1p[col0 + 1];
      int oc  = (col0 & 511) >> 6;
      int cc0 = ((col0 >> 9) << 6) | (col0 & 63);
      H2U p0; p0.h = h2{(h16)u00, (h16)u10};
      H2U p1; p1.h = h2{(h16)u01, (h16)u11};
      unsigned long long pk =
          (unsigned long long)p0.u | ((unsigned long long)p1.u << 32);
      cstoreu8((unsigned long long*)((h2*)(hb16 + HO_U16) +
                                     (size_t)oc * 65536 + (size_t)kp * 256 + cc0),
               pk);
    }
    if (t < 512) {
      float w0 = Wh[(size_t)(2 * kp) * DD + t];
      float w1 = Wh[(size_t)(2 * kp + 1) * DD + t];
      H2U pu; pu.h = h2{(h16)w0, (h16)w1};
      cstoreu((unsigned*)((h2*)(hb16 + HO_WH16) + (size_t)(t >> 6) * 16384 +
                          (size_t)kp * 64 + (t & 63)),
              pu.u);
    }
  }
  // 2) attc16 = fp16(ctx @ Wc + b_att): 16 rows per WG
  {
    float* fbuf = (float*)smem;  // 32 KB
    const int r0 = w * 16;
#pragma unroll
    for (int i = 0; i < 2; i++) {
      int idx4 = i * BD + t;
      int row = idx4 >> 7, c4 = idx4 & 127;
      ((float4*)fbuf)[idx4] = ((const float4*)(ctx + (size_t)(r0 + row) * DD))[c4];
    }
    __syncthreads();
    const int a0 = t & 511, rh = t >> 9;
    float acc[8];
#pragma unroll
    for (int r = 0; r < 8; r++) acc[r] = 0.f;
    for (int cc = 0; cc < DD; cc++) {
      float wv = Wc[(size_t)cc * DD + a0];
#pragma unroll
      for (int r = 0; r < 8; r++)
        acc[r] += fbuf[(8 * rh + r) * DD + cc] * wv;
    }
    const float ba = batt[a0];
    for (int r = 0; r < 8; r++)
      cstores(att16 + (size_t)(r0 + 8 * rh + r) * DD + a0, (h16)(acc[r] + ba));
    __syncthreads();
  }
  // 3) stage wprjL + biasS
  if (t < 64) wprjL[t] = wprj[oct * 64 + t];
  if (t < 256) biasS[t] = bias[(size_t)(t >> 6) * 512 + 64 * oct + (t & 63)];

  // 4) xw16[b][oct][st][cc] = fp16( x[b] @ W[:, cols(oct)] ), 8 chunks of 32 st
  {
    h2* xstage = (h2*)smem;  // [32][256]
    for (int chk = 0; chk < 8; chk++) {
      const int st0 = chk * 32;
      {
        const int row = t >> 5, seg = t & 31;
        const float* src = x + ((size_t)b * TSTEPS + st0 + row) * DD + seg * 16;
        h2* dst = xstage + row * 256 + seg * 8;
#pragma unroll
        for (int q = 0; q < 4; q++) {
          float4 v = *(const float4*)(src + 4 * q);
          dst[2 * q]     = h2{(h16)v.x, (h16)v.y};
          dst[2 * q + 1] = h2{(h16)v.z, (h16)v.w};
        }
      }
      __syncthreads();
      const int cc = t & 255, sq = t >> 8;
      const int col = ((cc >> 6) << 9) + 64 * oct + (cc & 63);
      float acc[8];
#pragma unroll
      for (int j = 0; j < 8; j++) acc[j] = 0.f;
#pragma unroll 2
      for (int kp = 0; kp < 256; kp++) {
        float w0 = W[(size_t)(2 * kp) * 2048 + col];
        float w1 = W[(size_t)(2 * kp + 1) * 2048 + col];
        h2 wp = h2{(h16)w0, (h16)w1};
#pragma unroll
        for (int j = 0; j < 8; j++)
          acc[j] = fdot2(xstage[(sq * 8 + j) * 256 + kp], wp, acc[j]);
      }
#pragma unroll
      for (int j = 0; j < 8; j++)
        cstores(xw16 + (((size_t)(b * 8 + oct) * 256) + st0 + sq * 8 + j) * 256 + cc,
                (h16)acc[j]);
      __syncthreads();
    }
  }
  // 5) ctxVp[b][oct][l][cc] = fp16( ctx[b] @ V[:, cols(oct)] ), 4 chunks of 32 l
  {
    h2* xstage = (h2*)smem;
    for (int chk = 0; chk < 4; chk++) {
      const int l0 = chk * 32;
      {
        const int row = t >> 5, seg = t & 31;
        const float* src = ctx + ((size_t)b * LC + l0 + row) * DD + seg * 16;
        h2* dst = xstage + row * 256 + seg * 8;
#pragma unroll
        for (int q = 0; q < 4; q++) {
          float4 v = *(const float4*)(src + 4 * q);
          dst[2 * q]     = h2{(h16)v.x, (h16)v.y};
          dst[2 * q + 1] = h2{(h16)v.z, (h16)v.w};
        }
      }
      __syncthreads();
      const int cc = t & 255, lq = t >> 8;
      const int col = ((cc >> 6) << 9) + 64 * oct + (cc & 63);
      float acc[8];
#pragma unroll
      for (int j = 0; j < 8; j++) acc[j] = 0.f;
#pragma unroll 2
      for (int kp = 0; kp < 256; kp++) {
        float v0 = V[(size_t)(2 * kp) * 2048 + col];
        float v1 = V[(size_t)(2 * kp + 1) * 2048 + col];
        h2 vp = h2{(h16)v0, (h16)v1};
#pragma unroll
        for (int j = 0; j < 8; j++)
          acc[j] = fdot2(xstage[(lq * 8 + j) * 256 + kp], vp, acc[j]);
      }
#pragma unroll
      for (int j = 0; j < 8; j++)
        cstores(ctxVp + (((size_t)(b * 8 + oct) * 128) + l0 + lq * 8 + j) * 256 + cc,
                (h16)acc[j]);
      __syncthreads();
    }
  }
  gsync(flags, rel, w, gen);

  // hoist ctxV into registers (step-invariant): thread (ccg=t&31, lq=t>>5)
  // owns l in {4lq..4lq+3}, cc in [8ccg, 8ccg+8)
  {
    const int ccg = t & 31, lq = t >> 5;
    const h16* cvb = ctxVp + ((size_t)(b * 8 + oct) * 128) * 256 + ccg * 8;
    pv0.v = *(const h8v*)(cvb + (lq * 4 + 0) * 256);
    pv1.v = *(const h8v*)(cvb + (lq * 4 + 1) * 256);
    pv2.v = *(const h8v*)(cvb + (lq * 4 + 2) * 256);
    pv3.v = *(const h8v*)(cvb + (lq * 4 + 3) * 256);
  }

  // ========== recurrence: 2 phases, 2 group barriers/step ==========
  for (int step = 0; step < TSTEPS; step++) {
    float xwv = 0.f;

    // ---- P1: h load; hU (256 cc); hatt (64 a, local); score partials (128 l) ----
    {
      if (t < 256) {
        unsigned hv = 0;
        if (step > 0)
          hv = *(const unsigned*)(hringB + ((size_t)b * TSTEPS + step - 1) * DD +
                                  2 * t);
        ((unsigned*)hLDS)[t] = hv;
      }
      __syncthreads();
      const int cc = t & 255, kq = t >> 8;
      const int kp0 = kq * 64;
      float f0 = 0.f, f1 = 0.f;
#pragma unroll 4
      for (int i = 0; i < 64; i += 2) {
        f0 = fdot2(hLDS[kp0 + i],     U2[(size_t)(kp0 + i) * 256 + cc],     f0);
        f1 = fdot2(hLDS[kp0 + i + 1], U2[(size_t)(kp0 + i + 1) * 256 + cc], f1);
      }
      red[kq * 256 + cc] = f0 + f1;
      if (t < 512) {
        const int a = t & 63, kg = t >> 6;
        const int kh0 = kg * 32;
        float ha = 0.f;
#pragma unroll 4
        for (int i = 0; i < 32; i++)
          ha = fdot2(hLDS[kh0 + i], Wh2[(size_t)(kh0 + i) * 64 + a], ha);
        red[1024 + kg * 64 + a] = ha;
      }
      // prefetch xw for this step (hidden under U2 stream)
      if (t < 256)
        xwv = (float)xw16[(((size_t)(b * 8 + oct) * 256) + step) * 256 + t];
      __syncthreads();
      if (t < 256) {
        hUk[t] = red[t] + red[256 + t] + red[512 + t] + red[768 + t];
      } else if (t < 320) {
        int a = t - 256;
        float ha = 0.f;
#pragma unroll
        for (int kg = 0; kg < 8; kg++) ha += red[1024 + kg * 64 + a];
        hattL[a] = ha;
      }
      __syncthreads();
      // partial scores over my a-slice for ALL 128 l (sum decomposes over a)
      {
        const int l = t >> 3, as = t & 7;
        H8 av;
        av.v = *(const h8v*)(att16 + (size_t)(b * LC + l) * DD + oct * 64 + as * 8);
        float p = 0.f;
#pragma unroll
        for (int j = 0; j < 8; j++)
          p += ftanh((float)av.v[j] + hattL[as * 8 + j]) * wprjL[as * 8 + j];
        p += __shfl_xor(p, 1); p += __shfl_xor(p, 2); p += __shfl_xor(p, 4);
        if (as == 0)
          cstoref(sexpP + ((size_t)b * 8 + oct) * 128 + l, p);
      }
    }
    gbar(gfl, oct, sg);

    // ---- P2: sum partials -> softmax -> PV (regs) -> preact -> gates -> h ----
    {
      // gather all 8 oct partials for batch b (4 KB coalesced)
      spp[t] = cloadf(sexpP + (size_t)b * 1024 + t);  // [oct'=t>>7][l=t&127]
      __syncthreads();
      if (t < 128) {
        float s = spp[t] + spp[128 + t] + spp[256 + t] + spp[384 + t] +
                  spp[512 + t] + spp[640 + t] + spp[768 + t] + spp[896 + t];
        sl[t] = __expf(s);
      }
      __syncthreads();
      if (t < 64) {
        float z = sl[t] + sl[t + 64];
        z += __shfl_xor(z, 32); z += __shfl_xor(z, 16); z += __shfl_xor(z, 8);
        z += __shfl_xor(z, 4);  z += __shfl_xor(z, 2);  z += __shfl_xor(z, 1);
        if (t == 0) *zinvS = rcp_fast(z);
      }
      const int ccg = t & 31, lq = t >> 5, w16 = t >> 6;
      float acc8[8];
#pragma unroll
      for (int j = 0; j < 8; j++) acc8[j] = 0.f;
      {
        float e0 = sl[lq * 4 + 0], e1 = sl[lq * 4 + 1];
        float e2 = sl[lq * 4 + 2], e3 = sl[lq * 4 + 3];
#pragma unroll
        for (int j = 0; j < 8; j++) {
          acc8[j] += e0 * (float)pv0.v[j];
          acc8[j] += e1 * (float)pv1.v[j];
          acc8[j] += e2 * (float)pv2.v[j];
          acc8[j] += e3 * (float)pv3.v[j];
        }
      }
#pragma unroll
      for (int j = 0; j < 8; j++) acc8[j] += __shfl_xor(acc8[j], 32);
      if ((t & 63) < 32) {
#pragma unroll
        for (int j = 0; j < 8; j++) red[w16 * 256 + ccg * 8 + j] = acc8[j];
      }
      __syncthreads();
      if (t < 256) {
        float pvs = 0.f;
#pragma unroll
        for (int k = 0; k < 16; k++) pvs += red[k * 256 + t];
        pre[t] = pvs * (*zinvS) + hUk[t] + xwv + biasS[t];
      }
      __syncthreads();
      if (t < 64) {
        const int d = t;
        float pi = pre[d], pf = pre[64 + d], po = pre[128 + d], pg = pre[192 + d];
        float ig = fsig(pi), fg = fsig(pf), og = fsig(po), gg = ftanh(pg);
        float cn = fg * c_reg + ig * gg;
        c_reg = cn;
        float hn = og * ftanh(cn);
        out[((size_t)b * TSTEPS + step) * DD + 64 * oct + d] = hn;
        cstores(hringB + ((size_t)b * TSTEPS + step) * DD + 64 * oct + d, (h16)hn);
      }
    }
    gbar(gfl, oct, sg);
  }
}

extern "C" void kernel_launch(void* const* d_in, const int* in_sizes, int n_in,
                              void* d_out, int out_size, void* d_ws, size_t ws_size,
                              hipStream_t stream) {
  (void)in_sizes; (void)n_in; (void)out_size; (void)ws_size;
  const float* x    = (const float*)d_in[0];
  const float* ctx  = (const float*)d_in[1];
  const float* W    = (const float*)d_in[2];
  const float* V    = (const float*)d_in[3];
  const float* U    = (const float*)d_in[4];
  const float* b    = (const float*)d_in[5];
  const float* Wh   = (const float*)d_in[6];
  const float* Wc   = (const float*)d_in[7];
  const float* batt = (const float*)d_in[8];
  const float* wprj = (const float*)d_in[9];

  // zero grid flags + rel + group flags
  hipMemsetAsync(d_ws, 0, (8192 + 256 + 8192) * sizeof(int), stream);

  hipLaunchKernelGGL(attn_lstm_persistent, dim3(GD), dim3(BD), 0, stream,
                     x, ctx, W, V, U, b, Wh, Wc, batt, wprj,
                     (float*)d_out, (float*)d_ws);
}

// Round 8
// 2421.850 us; speedup vs baseline: 2.8327x; 1.0550x over previous
//
#include <hip/hip_runtime.h>
#include <hip/hip_fp16.h>

#define GD 256   // 1 WG per CU, persistent
#define BD 1024  // 16 waves

constexpr int TSTEPS = 256;
constexpr int DD = 512;
constexpr int LC = 128;

// ---- ws float offsets ----
constexpr size_t OFF_FLAGS_F = 0;       // grid flags: 256 lines (stride 32 ints)
constexpr size_t OFF_REL_F   = 8192;    // 8 release lines
constexpr size_t OFF_GFLG_F  = 8448;    // group flags [8 xg][32 j][32 ints]
constexpr size_t OFF_HUX     = 16640;   // [32 b][2048 gcol] f32 hU exchange
constexpr size_t OFF_SCP     = 82176;   // [32 b][32 j][128 l] f32 score partials
constexpr size_t OFF_H16_F   = 213248;  // h16 base
// ---- h16-unit offsets ----
constexpr size_t HO_HX    = 0;          // [32 b][512] h (latest only)
constexpr size_t HO_ATT   = 16384;      // [4096 r][512] attc
constexpr size_t HO_U16   = 2113536;    // [8 oct][256 kp][256 cc] h2
constexpr size_t HO_WH16  = 3162112;    // [8 octa][256 kp][64 a] h2
constexpr size_t HO_CTXV  = 3424256;    // [32 b][8 oct][128 l][256 cc]
constexpr size_t HO_XW    = 11812864;   // [32 b][8 oct][256 st][256 cc]

typedef _Float16 h16;
typedef _Float16 h2  __attribute__((ext_vector_type(2)));
typedef _Float16 h8v __attribute__((ext_vector_type(8)));
union H8  { h8v v; h2 p[4]; };
union H2U { h2 h; unsigned u; };
union HSU { h16 h; unsigned short u; };

__device__ __forceinline__ float rcp_fast(float x) { return __builtin_amdgcn_rcpf(x); }
__device__ __forceinline__ float ftanh(float x) {
  float e = __expf(2.0f * x);
  return 1.0f - 2.0f * rcp_fast(e + 1.0f);
}
__device__ __forceinline__ float fsig(float x) { return rcp_fast(1.0f + __expf(-x)); }
__device__ __forceinline__ float fdot2(h2 a, h2 b, float c) {
  return __builtin_amdgcn_fdot2(a, b, c, false);
}

__device__ __forceinline__ float cloadf(const float* p) {
  return __hip_atomic_load(p, __ATOMIC_RELAXED, __HIP_MEMORY_SCOPE_AGENT);
}
__device__ __forceinline__ unsigned cloadu(const unsigned* p) {
  return __hip_atomic_load(p, __ATOMIC_RELAXED, __HIP_MEMORY_SCOPE_AGENT);
}
__device__ __forceinline__ void cstoref(float* p, float v) {
  __hip_atomic_store(p, v, __ATOMIC_RELAXED, __HIP_MEMORY_SCOPE_AGENT);
}
__device__ __forceinline__ void cstoreu(unsigned* p, unsigned v) {
  __hip_atomic_store(p, v, __ATOMIC_RELAXED, __HIP_MEMORY_SCOPE_AGENT);
}
__device__ __forceinline__ void cstoreu8(unsigned long long* p, unsigned long long v) {
  __hip_atomic_store(p, v, __ATOMIC_RELAXED, __HIP_MEMORY_SCOPE_AGENT);
}
__device__ __forceinline__ void cstores(h16* p, h16 v) {
  HSU s; s.h = v;
  __hip_atomic_store((unsigned short*)p, s.u, __ATOMIC_RELAXED,
                     __HIP_MEMORY_SCOPE_AGENT);
}

// grid barrier (setup only)
__device__ __forceinline__ void gsync(int* flags, int* rel, int w, int& gen) {
  __syncthreads();
  gen++;
  const int t = threadIdx.x;
  if (w == 0) {
    if (t < 64) {
      if (t == 0)
        __hip_atomic_store(flags, gen, __ATOMIC_RELAXED, __HIP_MEMORY_SCOPE_AGENT);
      for (;;) {
        int m = gen;
#pragma unroll
        for (int i = 0; i < 4; i++) {
          int v = __hip_atomic_load(flags + (t + i * 64) * 32,
                                    __ATOMIC_RELAXED, __HIP_MEMORY_SCOPE_AGENT);
          m = (v < m) ? v : m;
        }
        if (__all(m >= gen)) break;
      }
      if (t == 0) {
#pragma unroll
        for (int i = 0; i < 8; i++)
          __hip_atomic_store(rel + i * 32, gen, __ATOMIC_RELAXED,
                             __HIP_MEMORY_SCOPE_AGENT);
      }
    }
    asm volatile("" ::: "memory");
  } else {
    if (t == 0) {
      __hip_atomic_store(flags + w * 32, gen, __ATOMIC_RELAXED,
                         __HIP_MEMORY_SCOPE_AGENT);
      const int* r = rel + (w & 7) * 32;
      while (__hip_atomic_load(r, __ATOMIC_RELAXED, __HIP_MEMORY_SCOPE_AGENT) < gen)
        __builtin_amdgcn_s_sleep(1);
    }
    asm volatile("" ::: "memory");
  }
  __syncthreads();
}

// 32-WG group barrier: symmetric flag + poll
__device__ __forceinline__ void gbar32(int* gf, int j, int& sg) {
  __syncthreads();
  sg++;
  const int t = threadIdx.x;
  if (t < 64) {
    if (t == 0)
      __hip_atomic_store(gf + j * 32, sg, __ATOMIC_RELAXED,
                         __HIP_MEMORY_SCOPE_AGENT);
    for (;;) {
      int v = sg;
      if (t < 32)
        v = __hip_atomic_load(gf + t * 32, __ATOMIC_RELAXED,
                              __HIP_MEMORY_SCOPE_AGENT);
      if (__all(v >= sg)) break;
      __builtin_amdgcn_s_sleep(1);
    }
  }
  asm volatile("" ::: "memory");
  __syncthreads();
}

__global__ __launch_bounds__(BD, 4) void attn_lstm_persistent(
    const float* __restrict__ x, const float* __restrict__ ctx,
    const float* __restrict__ W, const float* __restrict__ V,
    const float* __restrict__ U, const float* __restrict__ bias,
    const float* __restrict__ Wh, const float* __restrict__ Wc,
    const float* __restrict__ batt, const float* __restrict__ wprj,
    float* __restrict__ out, float* __restrict__ ws) {
  __shared__ __align__(16) unsigned char smem[58448];
  h16*   attcL = (h16*)smem;                   // [512 row][18] (pad-18 banks)
  float* red   = (float*)(smem + 18432);       // 4096 f32
  float* red2  = (float*)(smem + 34816);       // 4096 f32
  h2*    hLDS  = (h2*)(smem + 51200);          // [4 q][256 kp]
  float* sl    = (float*)(smem + 55296);       // 128
  h2*    anL   = (h2*)(smem + 55808);          // 64 (fp16 alpha pairs)
  float* hattL = (float*)(smem + 56064);       // 64  ([q][16 a])
  float* wpL   = (float*)(smem + 56320);       // 16
  float* biasS = (float*)(smem + 56384);       // 256
  float* pre   = (float*)(smem + 57408);       // 256
  float* zinvS = (float*)(smem + 58432);       // 1

  const int w = blockIdx.x;
  const int t = threadIdx.x;
  // recurrence roles: group = same (blockIdx % 8) -> likely same XCD
  const int xg = w & 7;        // group id, batches [4xg, 4xg+4)
  const int j  = w >> 3;       // member 0..31: owns gcols [64j,64j+64), a [16j,16j+16)
  const int q2 = j >> 3;       // P2 batch-in-group
  const int bb = 4 * xg + q2;  // P2 batch
  const int oct = j & 7;       // P2 out-dims [64oct, 64oct+64)

  int* flags = (int*)(ws + OFF_FLAGS_F);
  int* rel   = (int*)(ws + OFF_REL_F);
  int* gfl   = (int*)(ws + OFF_GFLG_F) + xg * 1024;
  float* hUX = ws + OFF_HUX;
  float* scP = ws + OFF_SCP;
  h16* hb16  = (h16*)(ws + OFF_H16_F);
  h16* hX    = hb16 + HO_HX;
  h16* att16 = hb16 + HO_ATT;
  h16* ctxVp = hb16 + HO_CTXV;
  h16* xw16  = hb16 + HO_XW;

  int gen = 0, sg = 0;
  float c_reg = 0.f;           // t<64: c[bb][64oct + t]

  // ================= setup (verified packing, kept identical) =================
  {
    const int kp = w;
    {
      const float* r0p = U + (size_t)(2 * kp) * 2048;
      const float* r1p = r0p + 2048;
      const int col0 = 2 * t;
      float u00 = r0p[col0], u01 = r0p[col0 + 1];
      float u10 = r1p[col0], u11 = r1p[col0 + 1];
      int oc  = (col0 & 511) >> 6;
      int cc0 = ((col0 >> 9) << 6) | (col0 & 63);
      H2U p0; p0.h = h2{(h16)u00, (h16)u10};
      H2U p1; p1.h = h2{(h16)u01, (h16)u11};
      unsigned long long pk =
          (unsigned long long)p0.u | ((unsigned long long)p1.u << 32);
      cstoreu8((unsigned long long*)((h2*)(hb16 + HO_U16) +
                                     (size_t)oc * 65536 + (size_t)kp * 256 + cc0),
               pk);
    }
    if (t < 512) {
      float w0 = Wh[(size_t)(2 * kp) * DD + t];
      float w1 = Wh[(size_t)(2 * kp + 1) * DD + t];
      H2U pu; pu.h = h2{(h16)w0, (h16)w1};
      cstoreu((unsigned*)((h2*)(hb16 + HO_WH16) + (size_t)(t >> 6) * 16384 +
                          (size_t)kp * 64 + (t & 63)),
              pu.u);
    }
  }
  // attc16 = fp16(ctx @ Wc + b_att): 16 rows per WG
  {
    float* fbuf = (float*)smem;  // 32 KB staging (dead after gsync)
    const int r0 = w * 16;
#pragma unroll
    for (int i = 0; i < 2; i++) {
      int idx4 = i * BD + t;
      int row = idx4 >> 7, c4 = idx4 & 127;
      ((float4*)fbuf)[idx4] = ((const float4*)(ctx + (size_t)(r0 + row) * DD))[c4];
    }
    __syncthreads();
    const int a0 = t & 511, rh = t >> 9;
    float acc[8];
#pragma unroll
    for (int r = 0; r < 8; r++) acc[r] = 0.f;
    for (int cc = 0; cc < DD; cc++) {
      float wv = Wc[(size_t)cc * DD + a0];
#pragma unroll
      for (int r = 0; r < 8; r++)
        acc[r] += fbuf[(8 * rh + r) * DD + cc] * wv;
    }
    const float ba = batt[a0];
    for (int r = 0; r < 8; r++)
      cstores(att16 + (size_t)(r0 + 8 * rh + r) * DD + a0, (h16)(acc[r] + ba));
    __syncthreads();
  }
  // xw16 / ctxVp produced with setup-role (bS, octS) — layouts unchanged
  {
    const int bS = w >> 3, octS = w & 7;
    h2* xstage = (h2*)smem;  // [32][256]
    for (int chk = 0; chk < 8; chk++) {
      const int st0 = chk * 32;
      {
        const int row = t >> 5, seg = t & 31;
        const float* src = x + ((size_t)bS * TSTEPS + st0 + row) * DD + seg * 16;
        h2* dst = xstage + row * 256 + seg * 8;
#pragma unroll
        for (int q = 0; q < 4; q++) {
          float4 v = *(const float4*)(src + 4 * q);
          dst[2 * q]     = h2{(h16)v.x, (h16)v.y};
          dst[2 * q + 1] = h2{(h16)v.z, (h16)v.w};
        }
      }
      __syncthreads();
      const int cc = t & 255, sq = t >> 8;
      const int col = ((cc >> 6) << 9) + 64 * octS + (cc & 63);
      float acc[8];
#pragma unroll
      for (int jj = 0; jj < 8; jj++) acc[jj] = 0.f;
#pragma unroll 2
      for (int kp = 0; kp < 256; kp++) {
        float w0 = W[(size_t)(2 * kp) * 2048 + col];
        float w1 = W[(size_t)(2 * kp + 1) * 2048 + col];
        h2 wp = h2{(h16)w0, (h16)w1};
#pragma unroll
        for (int jj = 0; jj < 8; jj++)
          acc[jj] = fdot2(xstage[(sq * 8 + jj) * 256 + kp], wp, acc[jj]);
      }
#pragma unroll
      for (int jj = 0; jj < 8; jj++)
        cstores(xw16 + (((size_t)(bS * 8 + octS) * 256) + st0 + sq * 8 + jj) * 256 + cc,
                (h16)acc[jj]);
      __syncthreads();
    }
    for (int chk = 0; chk < 4; chk++) {
      const int l0 = chk * 32;
      {
        const int row = t >> 5, seg = t & 31;
        const float* src = ctx + ((size_t)bS * LC + l0 + row) * DD + seg * 16;
        h2* dst = xstage + row * 256 + seg * 8;
#pragma unroll
        for (int q = 0; q < 4; q++) {
          float4 v = *(const float4*)(src + 4 * q);
          dst[2 * q]     = h2{(h16)v.x, (h16)v.y};
          dst[2 * q + 1] = h2{(h16)v.z, (h16)v.w};
        }
      }
      __syncthreads();
      const int cc = t & 255, lq = t >> 8;
      const int col = ((cc >> 6) << 9) + 64 * octS + (cc & 63);
      float acc[8];
#pragma unroll
      for (int jj = 0; jj < 8; jj++) acc[jj] = 0.f;
#pragma unroll 2
      for (int kp = 0; kp < 256; kp++) {
        float v0 = V[(size_t)(2 * kp) * 2048 + col];
        float v1 = V[(size_t)(2 * kp + 1) * 2048 + col];
        h2 vp = h2{(h16)v0, (h16)v1};
#pragma unroll
        for (int jj = 0; jj < 8; jj++)
          acc[jj] = fdot2(xstage[(lq * 8 + jj) * 256 + kp], vp, acc[jj]);
      }
#pragma unroll
      for (int jj = 0; jj < 8; jj++)
        cstores(ctxVp + (((size_t)(bS * 8 + octS) * 128) + l0 + lq * 8 + jj) * 256 + cc,
                (h16)acc[jj]);
      __syncthreads();
    }
  }
  gsync(flags, rel, w, gen);

  // ======== load persistent operands: U->16 VGPR, Wh->4, ctxV->16, attc->LDS ====
  const int ccL = t & 63, kseg = t >> 6;   // hU: col 64j+ccL, kp in [16kseg,+16)
  const int aL = t & 15, ks2 = t >> 4;     // hatt: a 16j+aL, kp in [4ks2,+4)
  h2 u[16], wh[4], cvp01[8], cvp23[8];
  {
    const h2* Ub = (const h2*)(hb16 + HO_U16) + (size_t)(j & 7) * 65536 +
                   (size_t)(j >> 3) * 64 + ccL;
#pragma unroll
    for (int i = 0; i < 16; i++) u[i] = Ub[(size_t)(16 * kseg + i) * 256];
    const h2* Wb = (const h2*)(hb16 + HO_WH16) + (size_t)(j >> 2) * 16384 +
                   16 * (j & 3) + aL;
#pragma unroll
    for (int i = 0; i < 4; i++) wh[i] = Wb[(size_t)(4 * ks2 + i) * 64];
  }
  {
    const int ccg = t & 31, lq = t >> 5;
    const h16* cvb = ctxVp + ((size_t)(bb * 8 + oct) * 128) * 256 + ccg * 8;
    H8 p0, p1, p2, p3;
    p0.v = *(const h8v*)(cvb + (size_t)(4 * lq + 0) * 256);
    p1.v = *(const h8v*)(cvb + (size_t)(4 * lq + 1) * 256);
    p2.v = *(const h8v*)(cvb + (size_t)(4 * lq + 2) * 256);
    p3.v = *(const h8v*)(cvb + (size_t)(4 * lq + 3) * 256);
#pragma unroll
    for (int j8 = 0; j8 < 8; j8++) {
      cvp01[j8] = h2{p0.v[j8], p1.v[j8]};
      cvp23[j8] = h2{p2.v[j8], p3.v[j8]};
    }
  }
  {
    // attcL[row=q*128+l][18]: my 16 a-cols for 4 batches (one uint4 src per thread)
    const int row = t >> 1, half = t & 1, q = row >> 7, l = row & 127;
    uint4 v = *(const uint4*)(att16 + (size_t)((4 * xg + q) * LC + l) * DD +
                              16 * j + 8 * half);
    unsigned* dp = (unsigned*)(attcL + row * 18 + 8 * half);
    dp[0] = v.x; dp[1] = v.y; dp[2] = v.z; dp[3] = v.w;
  }
  if (t < 16) wpL[t] = wprj[16 * j + t];
  if (t < 256) biasS[t] = bias[(size_t)(t >> 6) * 512 + 64 * oct + (t & 63)];
  __syncthreads();

  // ========== recurrence: 2 phases, 2 group barriers/step ==========
  for (int step = 0; step < TSTEPS; step++) {
    // ---- P1: h gather; hU (regs) + hatt (regs) partials; scores (my 16 a) ----
    {
      unsigned hv = 0;
      if (step > 0)
        hv = cloadu((const unsigned*)(hX + (size_t)(4 * xg + (t >> 8)) * DD +
                                      2 * (t & 255)));
      ((unsigned*)hLDS)[t] = hv;
      __syncthreads();
      // hU partials: 4 batches x 16 fdot2
      {
        float f0 = 0.f, f1 = 0.f, f2 = 0.f, f3 = 0.f;
        const int base = 16 * kseg;
#pragma unroll
        for (int i = 0; i < 16; i++) {
          h2 uu = u[i];
          f0 = fdot2(hLDS[base + i], uu, f0);
          f1 = fdot2(hLDS[256 + base + i], uu, f1);
          f2 = fdot2(hLDS[512 + base + i], uu, f2);
          f3 = fdot2(hLDS[768 + base + i], uu, f3);
        }
        red[kseg * 256 + ccL]       = f0;
        red[kseg * 256 + 64 + ccL]  = f1;
        red[kseg * 256 + 128 + ccL] = f2;
        red[kseg * 256 + 192 + ccL] = f3;
      }
      // hatt partials: 4 batches x 4 fdot2
      {
        float g0 = 0.f, g1 = 0.f, g2 = 0.f, g3 = 0.f;
        const int base = 4 * ks2;
#pragma unroll
        for (int i = 0; i < 4; i++) {
          h2 ww = wh[i];
          g0 = fdot2(hLDS[base + i], ww, g0);
          g1 = fdot2(hLDS[256 + base + i], ww, g1);
          g2 = fdot2(hLDS[512 + base + i], ww, g2);
          g3 = fdot2(hLDS[768 + base + i], ww, g3);
        }
        red2[ks2 * 64 + aL]      = g0;
        red2[ks2 * 64 + 16 + aL] = g1;
        red2[ks2 * 64 + 32 + aL] = g2;
        red2[ks2 * 64 + 48 + aL] = g3;
      }
      __syncthreads();
      if (t < 256) {  // hU reduce + publish (gcol = 64j + cc)
        float s = 0.f;
#pragma unroll
        for (int k = 0; k < 16; k++) s += red[k * 256 + t];
        cstoref(hUX + (size_t)(4 * xg + (t >> 6)) * 2048 + 64 * j + (t & 63), s);
      } else if (t < 320) {  // hatt reduce -> hattL[q*16+aL]
        const int r = t - 256;
        float s = 0.f;
#pragma unroll
        for (int k = 0; k < 64; k++) s += red2[k * 64 + r];
        hattL[r] = s;
      }
      __syncthreads();
      // score partials over my 16 a, all 4 batches x 128 l
      {
        const int row = t >> 1, half = t & 1, q = row >> 7;
        const h16* arow = attcL + row * 18 + 8 * half;
        const float* hb_ = hattL + q * 16 + 8 * half;
        const float* wp_ = wpL + 8 * half;
        float p = 0.f;
#pragma unroll
        for (int aa = 0; aa < 8; aa++)
          p += ftanh((float)arow[aa] + hb_[aa]) * wp_[aa];
        p += __shfl_xor(p, 1);
        if (half == 0)
          cstoref(scP + (size_t)(4 * xg + q) * 4096 + j * 128 + (row & 127), p);
      }
    }
    gbar32(gfl, j, sg);

    // ---- P2: sum 32 partials -> softmax -> PV(fdot2 regs) -> gates -> h ----
    {
      float hUv = 0.f, xwv = 0.f;
      if (t < 256) {
        hUv = cloadf(hUX + (size_t)bb * 2048 + (size_t)(t >> 6) * 512 +
                     64 * oct + (t & 63));
        xwv = (float)xw16[(((size_t)(bb * 8 + oct)) * 256 + step) * 256 + t];
      }
#pragma unroll
      for (int r = 0; r < 4; r++)
        red[r * 1024 + t] = cloadf(scP + (size_t)bb * 4096 + r * 1024 + t);
      __syncthreads();
      if (t < 128) {
        float s = 0.f;
#pragma unroll
        for (int jj = 0; jj < 32; jj++) s += red[jj * 128 + t];
        sl[t] = __expf(s);
      }
      __syncthreads();
      if (t < 64) {
        float z = sl[t] + sl[t + 64];
        z += __shfl_xor(z, 32); z += __shfl_xor(z, 16); z += __shfl_xor(z, 8);
        z += __shfl_xor(z, 4);  z += __shfl_xor(z, 2);  z += __shfl_xor(z, 1);
        if (t == 0) *zinvS = rcp_fast(z);
      }
      __syncthreads();
      if (t < 64) {
        float zi = *zinvS;
        anL[t] = h2{(h16)(sl[2 * t] * zi), (h16)(sl[2 * t + 1] * zi)};
      }
      __syncthreads();
      {
        const int ccg = t & 31, lq = t >> 5, w16 = t >> 6;
        h2 a01 = anL[2 * lq], a23 = anL[2 * lq + 1];
        float acc8[8];
#pragma unroll
        for (int j8 = 0; j8 < 8; j8++)
          acc8[j8] = fdot2(a23, cvp23[j8], fdot2(a01, cvp01[j8], 0.f));
#pragma unroll
        for (int j8 = 0; j8 < 8; j8++) acc8[j8] += __shfl_xor(acc8[j8], 32);
        if ((t & 63) < 32) {
#pragma unroll
          for (int j8 = 0; j8 < 8; j8++)
            red[w16 * 256 + ccg * 8 + j8] = acc8[j8];
        }
      }
      __syncthreads();
      if (t < 256) {
        float pvs = 0.f;
#pragma unroll
        for (int k = 0; k < 16; k++) pvs += red[k * 256 + t];
        pre[t] = pvs + hUv + xwv + biasS[t];  // pvs already normalized
      }
      __syncthreads();
      if (t < 64) {
        const int d = t;
        float pi = pre[d], pf = pre[64 + d], po = pre[128 + d], pg = pre[192 + d];
        float ig = fsig(pi), fg = fsig(pf), og = fsig(po), gg = ftanh(pg);
        float cn = fg * c_reg + ig * gg;
        c_reg = cn;
        float hn = og * ftanh(cn);
        out[((size_t)bb * TSTEPS + step) * DD + 64 * oct + d] = hn;
        cstores(hX + (size_t)bb * DD + 64 * oct + d, (h16)hn);
      }
    }
    gbar32(gfl, j, sg);
  }
}

extern "C" void kernel_launch(void* const* d_in, const int* in_sizes, int n_in,
                              void* d_out, int out_size, void* d_ws, size_t ws_size,
                              hipStream_t stream) {
  (void)in_sizes; (void)n_in; (void)out_size; (void)ws_size;
  const float* x    = (const float*)d_in[0];
  const float* ctx  = (const float*)d_in[1];
  const float* W    = (const float*)d_in[2];
  const float* V    = (const float*)d_in[3];
  const float* U    = (const float*)d_in[4];
  const float* b    = (const float*)d_in[5];
  const float* Wh   = (const float*)d_in[6];
  const float* Wc   = (const float*)d_in[7];
  const float* batt = (const float*)d_in[8];
  const float* wprj = (const float*)d_in[9];

  // zero grid flags + rel + group flags
  hipMemsetAsync(d_ws, 0, (8192 + 256 + 8192) * sizeof(int), stream);

  hipLaunchKernelGGL(attn_lstm_persistent, dim3(GD), dim3(BD), 0, stream,
                     x, ctx, W, V, U, b, Wh, Wc, batt, wprj,
                     (float*)d_out, (float*)d_ws);
}